// Round 2
// baseline (76.063 us; speedup 1.0000x reference)
//
#include <hip/hip_runtime.h>
#include <math.h>

// Problem: S=4096, B=16, H=1024
//   energies[b,s] = hidden[b,:] . (W @ enc[s,b,:] + b_attn)
//   out[b,0,s]    = softmax_s(energies[b,s])
//
// Reassociated: energies[b,s] = v[b,:] . enc[s,b,:] + hidden[b].b_attn
//   with v = hidden @ W. The bias term is constant over s -> cancels in
//   softmax (shift invariance), so b_attn is never read.
//
// Structure (4 launches):
//   A1: split-k partial GEMV   (1024 blocks, 64-deep loops)
//   A2: reduce 16 partials -> v (64 blocks)
//   B : energies, v in registers, 8 enc rows per wave, nontemporal enc loads
//   C : softmax per b (16 blocks), in-place on d_out

#define SS 4096
#define BB 16
#define HH 1024
#define KC 16          // k-chunks for split-k GEMV
#define KLEN (HH / KC) // 64
#define PP 8           // enc rows (pairs) per wave in kernel B

typedef float f4 __attribute__((ext_vector_type(4)));

// ---- A1: partial[kc][b*HH+h] = sum_{k in chunk kc} hidden[b,k] * W[k,h] ----
// 1024 blocks x 256 threads. Block -> (kc, b, h-chunk of 256): W reads are
// coalesced over h; hidden[b,k] is block-uniform (scalar loads).
__global__ void gemv_partial_kernel(const float* __restrict__ hidden,
                                    const float* __restrict__ W,
                                    float* __restrict__ partial) {
    int blk = blockIdx.x;          // 0..1023
    int kc  = blk >> 6;            // 16 chunks
    int rb  = blk & 63;            // b(16) x hchunk(4)
    int b   = rb >> 2;
    int h   = ((rb & 3) << 8) | threadIdx.x;
    const float* hrow = hidden + b * HH + kc * KLEN;
    const float* Wp   = W + (size_t)(kc * KLEN) * HH + h;
    float a0 = 0.f, a1 = 0.f, a2 = 0.f, a3 = 0.f;
    #pragma unroll 4
    for (int k = 0; k < KLEN; k += 4) {
        a0 += hrow[k + 0] * Wp[(k + 0) * HH];
        a1 += hrow[k + 1] * Wp[(k + 1) * HH];
        a2 += hrow[k + 2] * Wp[(k + 2) * HH];
        a3 += hrow[k + 3] * Wp[(k + 3) * HH];
    }
    partial[kc * (BB * HH) + b * HH + h] = (a0 + a1) + (a2 + a3);
}

// ---- A2: v[i] = sum_kc partial[kc][i] ------------------------------------
__global__ void gemv_reduce_kernel(const float* __restrict__ partial,
                                   float* __restrict__ v) {
    int i = blockIdx.x * 256 + threadIdx.x;   // 0..16383
    float s = 0.f;
    #pragma unroll
    for (int kc = 0; kc < KC; ++kc) s += partial[kc * (BB * HH) + i];
    v[i] = s;
}

// ---- B: energies[b,s] = v[b,:] . enc[s,b,:] ------------------------------
// One wave per 8 pairs sharing the same b. The wave's v row (4 KB) lives in
// 16 VGPRs (loaded once); each pair is 4x float4 nontemporal loads of enc
// (64 lanes x 16 B = 1 KB coalesced), elementwise FMA, then a 6-step
// shfl_xor reduce. enc rows for pair p=(s*B+b) start at p*H: contiguous 4 KB.
__global__ void energies_kernel(const float* __restrict__ enc,
                                const float* __restrict__ v,
                                float* __restrict__ out) {
    int w    = (blockIdx.x * blockDim.x + threadIdx.x) >> 6;  // wave id 0..8191
    int lane = threadIdx.x & 63;
    int b  = w & (BB - 1);
    int sg = w >> 4;               // 0..511, covers s in [sg*PP, sg*PP+PP)
    const f4* v4 = (const f4*)(v + b * HH);
    f4 vv[4];
    #pragma unroll
    for (int i = 0; i < 4; ++i) vv[i] = v4[i * 64 + lane];
    float acc[PP];
    #pragma unroll
    for (int j = 0; j < PP; ++j) {
        int s = sg * PP + j;
        const f4* e4 = (const f4*)(enc + (size_t)(s * BB + b) * HH);
        f4 a0 = __builtin_nontemporal_load(&e4[0 * 64 + lane]);
        f4 a1 = __builtin_nontemporal_load(&e4[1 * 64 + lane]);
        f4 a2 = __builtin_nontemporal_load(&e4[2 * 64 + lane]);
        f4 a3 = __builtin_nontemporal_load(&e4[3 * 64 + lane]);
        f4 prod = a0 * vv[0] + a1 * vv[1] + a2 * vv[2] + a3 * vv[3];
        acc[j] = (prod.x + prod.y) + (prod.z + prod.w);
    }
    #pragma unroll
    for (int j = 0; j < PP; ++j) {
        float a = acc[j];
        #pragma unroll
        for (int off = 32; off; off >>= 1) a += __shfl_xor(a, off, 64);
        if (lane == 0) out[b * SS + sg * PP + j] = a;
    }
}

// ---- C: in-place softmax over s, one 256-thread block per b --------------
__global__ void softmax_kernel(float* __restrict__ out) {
    int b = blockIdx.x;
    float* row = out + b * SS;
    int t = threadIdx.x;                 // 16 values per thread
    float vals[16];
    float m = -INFINITY;
    #pragma unroll
    for (int i = 0; i < 16; ++i) {
        vals[i] = row[t + i * 256];
        m = fmaxf(m, vals[i]);
    }
    #pragma unroll
    for (int off = 32; off; off >>= 1) m = fmaxf(m, __shfl_xor(m, off, 64));
    __shared__ float redm[4];
    __shared__ float reds[4];
    int wid = t >> 6;
    if ((t & 63) == 0) redm[wid] = m;
    __syncthreads();
    m = fmaxf(fmaxf(redm[0], redm[1]), fmaxf(redm[2], redm[3]));

    float sum = 0.f;
    #pragma unroll
    for (int i = 0; i < 16; ++i) {
        vals[i] = expf(vals[i] - m);
        sum += vals[i];
    }
    #pragma unroll
    for (int off = 32; off; off >>= 1) sum += __shfl_xor(sum, off, 64);
    if ((t & 63) == 0) reds[wid] = sum;
    __syncthreads();
    sum = reds[0] + reds[1] + reds[2] + reds[3];
    float inv = 1.0f / sum;
    #pragma unroll
    for (int i = 0; i < 16; ++i) row[t + i * 256] = vals[i] * inv;
}

extern "C" void kernel_launch(void* const* d_in, const int* in_sizes, int n_in,
                              void* d_out, int out_size, void* d_ws, size_t ws_size,
                              hipStream_t stream) {
    const float* hidden = (const float*)d_in[0];   // [1,B,H]
    const float* enc    = (const float*)d_in[1];   // [S,B,H]
    const float* W      = (const float*)d_in[2];   // [H,H]
    // d_in[3] = b_attn: cancels in softmax (and is zero in setup_inputs)
    float* out     = (float*)d_out;                // [B,1,S]
    float* v       = (float*)d_ws;                 // B*H floats   = 64 KB
    float* partial = v + BB * HH;                  // KC*B*H floats = 1 MB

    hipLaunchKernelGGL(gemv_partial_kernel, dim3(KC * 64), dim3(256), 0, stream,
                       hidden, W, partial);
    hipLaunchKernelGGL(gemv_reduce_kernel, dim3(BB * HH / 256), dim3(256), 0, stream,
                       partial, v);
    hipLaunchKernelGGL(energies_kernel, dim3(SS * BB / PP / 4), dim3(256), 0, stream,
                       enc, v, out);
    hipLaunchKernelGGL(softmax_kernel, dim3(BB), dim3(256), 0, stream, out);
}